// Round 1
// baseline (869.187 us; speedup 1.0000x reference)
//
#include <hip/hip_runtime.h>
#include <math.h>

// Router: logits = x @ Wg ; probs = softmax(logits) ; top-2 ; combine = topk/sum(topk)
// T=65536, D=1024, E=64. Output flat fp32: [combine 2T][idx-as-float 2T][probs 64T].
//
// Layout choice: thread == token. Lane holds all E=64 fp32 accumulators in VGPRs,
// so softmax + top-2 are thread-local (no cross-lane). Weights Wg[d][*] are
// wave-uniform -> scalar loads (SMEM pipe), x comes from LDS (padded stride 36
// -> uniform 8-accesses/bank for stride-36 b128 reads = LDS peak).

#define D_DIM 1024
#define E_DIM 64
#define TPB 256     // threads per block == tokens per block
#define DC 32       // D-chunk staged in LDS per iteration
#define DS 36       // padded LDS row stride in floats (multiple of 4 for b128 align)

__global__ __launch_bounds__(TPB) void router_kernel(
    const float* __restrict__ x, const float* __restrict__ Wg,
    float* __restrict__ out, int T)
{
    __shared__ float sx[TPB * DS];

    const int tid   = threadIdx.x;
    const int base  = blockIdx.x * TPB;
    const int token = base + tid;

    float acc[E_DIM];
#pragma unroll
    for (int e = 0; e < E_DIM; ++e) acc[e] = 0.0f;

    // Staging map: 256 threads load 256 tokens x 32 floats per chunk.
    // 8 consecutive threads cover one 32-float row (8 x float4), rows advance by 32.
    const int srow = tid >> 3;          // 0..31
    const int scol = (tid & 7) << 2;    // 0,4,...,28

    float4 stage[8];
#pragma unroll
    for (int p = 0; p < 8; ++p) {
        const int t = srow + p * 32;
        stage[p] = *(const float4*)&x[(size_t)(base + t) * D_DIM + scol];
    }

    for (int dc = 0; dc < D_DIM; dc += DC) {
        __syncthreads();   // previous chunk's LDS reads done
#pragma unroll
        for (int p = 0; p < 8; ++p) {
            const int t = srow + p * 32;
            *(float4*)&sx[t * DS + scol] = stage[p];
        }
        __syncthreads();   // tile visible

        const int dn = dc + DC;
        if (dn < D_DIM) {
            // issue next chunk's global loads now; they complete under the FMAs
#pragma unroll
            for (int p = 0; p < 8; ++p) {
                const int t = srow + p * 32;
                stage[p] = *(const float4*)&x[(size_t)(base + t) * D_DIM + dn + scol];
            }
        }

        for (int j = 0; j < DC; j += 4) {
            const float4 xv = *(const float4*)&sx[tid * DS + j];
            const float* __restrict__ w0 = &Wg[(size_t)(dc + j) * E_DIM];
            const float* __restrict__ w1 = w0 + E_DIM;
            const float* __restrict__ w2 = w1 + E_DIM;
            const float* __restrict__ w3 = w2 + E_DIM;
#pragma unroll
            for (int e = 0; e < E_DIM; ++e) acc[e] = fmaf(xv.x, w0[e], acc[e]);
#pragma unroll
            for (int e = 0; e < E_DIM; ++e) acc[e] = fmaf(xv.y, w1[e], acc[e]);
#pragma unroll
            for (int e = 0; e < E_DIM; ++e) acc[e] = fmaf(xv.z, w2[e], acc[e]);
#pragma unroll
            for (int e = 0; e < E_DIM; ++e) acc[e] = fmaf(xv.w, w3[e], acc[e]);
        }
    }

    // ---- softmax (numpy-style: exp(x - max) / sum) ----
    float m = acc[0];
#pragma unroll
    for (int e = 1; e < E_DIM; ++e) m = fmaxf(m, acc[e]);

    float s = 0.0f;
#pragma unroll
    for (int e = 0; e < E_DIM; ++e) {
        const float p = expf(acc[e] - m);
        acc[e] = p;
        s += p;
    }
    const float inv = 1.0f / s;

    // ---- top-2 with lowest-index-on-tie (strict >) ----
    float v1 = -1.0f, v2 = -1.0f;
    int   i1 = 0,     i2 = 0;
#pragma unroll
    for (int e = 0; e < E_DIM; ++e) {
        const float p = acc[e] * inv;
        acc[e] = p;
        if (p > v1)      { v2 = v1; i2 = i1; v1 = p; i1 = e; }
        else if (p > v2) { v2 = p;  i2 = e; }
    }

    const float denom = v1 + v2;

    // combine [2T] -- coalesced float2
    *(float2*)&out[(size_t)2 * token] = make_float2(v1 / denom, v2 / denom);
    // idx as float [2T]
    *(float2*)&out[(size_t)2 * T + (size_t)2 * token] = make_float2((float)i1, (float)i2);
    // probs [64T]
    float* po = out + (size_t)4 * T + (size_t)token * E_DIM;
#pragma unroll
    for (int j = 0; j < E_DIM; j += 4) {
        *(float4*)&po[j] = make_float4(acc[j], acc[j + 1], acc[j + 2], acc[j + 3]);
    }
}

extern "C" void kernel_launch(void* const* d_in, const int* in_sizes, int n_in,
                              void* d_out, int out_size, void* d_ws, size_t ws_size,
                              hipStream_t stream) {
    const float* x  = (const float*)d_in[0];
    const float* Wg = (const float*)d_in[1];
    float* out = (float*)d_out;
    const int T = in_sizes[0] / D_DIM;   // 65536

    router_kernel<<<dim3(T / TPB), dim3(TPB), 0, stream>>>(x, Wg, out, T);
}

// Round 2
// 542.662 us; speedup vs baseline: 1.6017x; 1.6017x over previous
//
#include <hip/hip_runtime.h>
#include <math.h>

// Router: logits = x @ Wg ; probs = softmax ; top-2 ; combine renormalized.
// T=65536, D=1024, E=64. Out flat fp32: [combine 2T][idx-as-float 2T][probs 64T].
//
// R2: 4-way expert split. wave q = tid>>6 computes 16 experts for 64 tokens
// (lane==token_local). Grid 1024 blocks -> 4 blocks/CU, 16 waves/CU (vs 4 in R1).
// Weight addresses made wave-uniform via readfirstlane -> scalar s_load path.
// Probs written coalesced through LDS (fixes 5x write amplification).

#define D_DIM 1024
#define E_DIM 64
#define TPB   256
#define TOK   64      // tokens per block
#define EPT   16      // experts per thread (= E_DIM / 4 waves)
#define DC    32      // D-chunk staged in LDS
#define XS    36      // x-tile row stride (floats): stride-36 b128 is conflict-free (R1: 0 conflicts)
#define LS    65      // logits row stride (floats): (65t+e)%32 distinct across lanes -> conflict-free scalar

__global__ __launch_bounds__(TPB) void router_kernel(
    const float* __restrict__ x, const float* __restrict__ Wg,
    float* __restrict__ out, int T)
{
    __shared__ float sx[TOK * XS];
    __shared__ float sl[TOK * LS];

    const int tid  = threadIdx.x;
    const int lane = tid & 63;                                  // token within block
    const int q    = __builtin_amdgcn_readfirstlane(tid >> 6);  // expert quarter, wave-uniform
    const int base = blockIdx.x * TOK;

    float acc[EPT];
#pragma unroll
    for (int e = 0; e < EPT; ++e) acc[e] = 0.0f;

    // Staging map: 2048 floats/chunk, 256 threads -> 2 float4 each.
    const int srow = tid >> 3;          // 0..31 (and +32 for the second vector)
    const int scol = (tid & 7) << 2;    // 0,4,...,28

    float4 st0 = *(const float4*)&x[(size_t)(base + srow)      * D_DIM + scol];
    float4 st1 = *(const float4*)&x[(size_t)(base + srow + 32) * D_DIM + scol];

    for (int dc = 0; dc < D_DIM; dc += DC) {
        __syncthreads();
        *(float4*)&sx[srow * XS + scol]        = st0;
        *(float4*)&sx[(srow + 32) * XS + scol] = st1;
        __syncthreads();

        const int dn = dc + DC;
        if (dn < D_DIM) {   // prefetch next chunk under this chunk's FMAs
            st0 = *(const float4*)&x[(size_t)(base + srow)      * D_DIM + dn + scol];
            st1 = *(const float4*)&x[(size_t)(base + srow + 32) * D_DIM + dn + scol];
        }

        for (int j = 0; j < DC; j += 4) {
            const float4 xv = *(const float4*)&sx[lane * XS + j];
            const float* __restrict__ wr = Wg + (size_t)(dc + j) * E_DIM + q * EPT;
#pragma unroll
            for (int e = 0; e < EPT; ++e) acc[e] = fmaf(xv.x, wr[e], acc[e]);
            wr += E_DIM;
#pragma unroll
            for (int e = 0; e < EPT; ++e) acc[e] = fmaf(xv.y, wr[e], acc[e]);
            wr += E_DIM;
#pragma unroll
            for (int e = 0; e < EPT; ++e) acc[e] = fmaf(xv.z, wr[e], acc[e]);
            wr += E_DIM;
#pragma unroll
            for (int e = 0; e < EPT; ++e) acc[e] = fmaf(xv.w, wr[e], acc[e]);
        }
    }

    // ---- logits -> LDS (conflict-free: bank (65*lane + q*16 + e) % 32 distinct per lane) ----
#pragma unroll
    for (int e = 0; e < EPT; ++e) sl[lane * LS + q * EPT + e] = acc[e];
    __syncthreads();

    // ---- epilogue: wave 0, one thread per token; LDS-resident to keep VGPRs low ----
    if (tid < TOK) {
        const int t = tid;
        float m = -INFINITY;
#pragma unroll
        for (int e = 0; e < E_DIM; ++e) m = fmaxf(m, sl[t * LS + e]);

        float s = 0.0f;
#pragma unroll
        for (int e = 0; e < E_DIM; ++e) {
            const float p = expf(sl[t * LS + e] - m);
            sl[t * LS + e] = p;
            s += p;
        }
        const float inv = 1.0f / s;

        float v1 = -1.0f, v2 = -1.0f;
        int   i1 = 0,     i2 = 0;
#pragma unroll
        for (int e = 0; e < E_DIM; ++e) {
            const float p = sl[t * LS + e] * inv;   // normalize preserves order
            sl[t * LS + e] = p;
            if (p > v1)      { v2 = v1; i2 = i1; v1 = p; i1 = e; }
            else if (p > v2) { v2 = p;  i2 = e; }
        }

        const float denom = v1 + v2;
        const int token = base + t;
        *(float2*)&out[(size_t)2 * token]                   = make_float2(v1 / denom, v2 / denom);
        *(float2*)&out[(size_t)2 * T + (size_t)2 * token]   = make_float2((float)i1, (float)i2);
    }
    __syncthreads();

    // ---- coalesced probs write: block's 16 KB region written as linear float4s ----
    float* __restrict__ po = out + (size_t)4 * T + (size_t)base * E_DIM;
#pragma unroll
    for (int k = 0; k < 4; ++k) {
        const int g = (tid + k * TPB) << 2;    // float offset in block region
        const int t = g >> 6;
        const int e = g & 63;
        const float4 v = make_float4(sl[t * LS + e],     sl[t * LS + e + 1],
                                     sl[t * LS + e + 2], sl[t * LS + e + 3]);
        *(float4*)&po[g] = v;
    }
}

extern "C" void kernel_launch(void* const* d_in, const int* in_sizes, int n_in,
                              void* d_out, int out_size, void* d_ws, size_t ws_size,
                              hipStream_t stream) {
    const float* x  = (const float*)d_in[0];
    const float* Wg = (const float*)d_in[1];
    float* out = (float*)d_out;
    const int T = in_sizes[0] / D_DIM;   // 65536

    router_kernel<<<dim3(T / TOK), dim3(TPB), 0, stream>>>(x, Wg, out, T);
}

// Round 3
// 514.009 us; speedup vs baseline: 1.6910x; 1.0557x over previous
//
#include <hip/hip_runtime.h>
#include <math.h>

// Router: logits = x@Wg ; softmax ; top-2 ; renormalized combine.
// T=65536, D=1024, E=64. Out flat fp32: [combine 2T][idx-as-float 2T][probs 64T].
//
// R3: register outer-product tile. Lane owns 8 tokens x 4 experts (32 acc VGPRs).
// Per 4 d-rows: 8 x-frags + 4 w-frags (b128 from LDS) -> 128 independent FMAs.
// Weights staged in LDS (no SMEM in hot loop -> DS-only lgkmcnt, fine-grained waits).
// Double-buffered LDS, 1 barrier/chunk, global prefetch a full chunk ahead.
// Summation order d-ascending per expert == R2 (bit-identical numerics).

#define D_DIM 1024
#define E_DIM 64
#define TPB   128
#define TOK   64        // tokens per block
#define DC    32        // d-rows per chunk
#define NCH   (D_DIM / DC)
#define XS    36        // x tile stride (floats); 144 B = 9*16 -> b128-aligned, measured 0-conflict
#define WSd   64        // w tile stride
#define LS    65        // logits tile stride (scalar access, odd -> conflict-free)

__global__ __launch_bounds__(TPB, 2) void router_kernel(
    const float* __restrict__ x, const float* __restrict__ Wg,
    float* __restrict__ out, int T)
{
    __shared__ float sx[2][TOK * XS];   // 18432 B
    __shared__ float sw[2][DC * WSd];   // 16384 B   (total 34816 B -> 4 blocks/CU)

    const int tid  = threadIdx.x;
    const int lane = tid & 63;
    const int wv   = __builtin_amdgcn_readfirstlane(tid >> 6);  // wave: experts 0-31 / 32-63
    const int tr   = lane >> 3;          // token row: lane's tokens are tr + 8i (strided!)
    const int ec   = lane & 7;           // expert col: lane's experts are wv*32 + ec*4 + j
    const int we   = wv * 32 + (ec << 2);
    const int base = blockIdx.x * TOK;

    float acc[8][4];
#pragma unroll
    for (int i = 0; i < 8; ++i)
#pragma unroll
        for (int j = 0; j < 4; ++j) acc[i][j] = 0.0f;

    // staging maps: x chunk = 64 tok x 32 d = 512 float4; w chunk = 32 d x 64 e = 512 float4
    int xt[4], xc[4], wr_[4], wc[4];
#pragma unroll
    for (int p = 0; p < 4; ++p) {
        const int vid = tid + p * TPB;
        xt[p]  = vid >> 3;          // 0..63
        xc[p]  = (vid & 7) << 2;    // 0..28
        wr_[p] = vid >> 4;          // 0..31
        wc[p]  = (vid & 15) << 2;   // 0..60
    }

    float4 xst[4], wst[4];

#define LOAD_CHUNK(dc)                                                              \
    {                                                                               \
        _Pragma("unroll")                                                           \
        for (int p = 0; p < 4; ++p)                                                 \
            xst[p] = *(const float4*)&x[(size_t)(base + xt[p]) * D_DIM + (dc) + xc[p]]; \
        _Pragma("unroll")                                                           \
        for (int p = 0; p < 4; ++p)                                                 \
            wst[p] = *(const float4*)&Wg[(size_t)((dc) + wr_[p]) * E_DIM + wc[p]];  \
    }

#define WRITE_CHUNK(b)                                                              \
    {                                                                               \
        _Pragma("unroll")                                                           \
        for (int p = 0; p < 4; ++p) *(float4*)&sx[b][xt[p] * XS + xc[p]] = xst[p];  \
        _Pragma("unroll")                                                           \
        for (int p = 0; p < 4; ++p) *(float4*)&sw[b][wr_[p] * WSd + wc[p]] = wst[p];\
    }

    LOAD_CHUNK(0)
    WRITE_CHUNK(0)
    LOAD_CHUNK(DC)
    __syncthreads();

    for (int ch = 0; ch < NCH; ++ch) {
        const int cur = ch & 1;
        if (ch + 1 < NCH) WRITE_CHUNK(ch & 1 ? 0 : 1)        // chunk ch+1 regs -> other buffer
        if (ch + 2 < NCH) LOAD_CHUNK((ch + 2) * DC)          // prefetch 2 ahead

        const float* __restrict__ bx = sx[cur];
        const float* __restrict__ bw = sw[cur];

#pragma unroll 2
        for (int g = 0; g < DC; g += 4) {
            float4 xf[8];
            float4 wf[4];
#pragma unroll
            for (int i = 0; i < 8; ++i)
                xf[i] = *(const float4*)&bx[(tr + 8 * i) * XS + g];     // broadcast x8 over ec
#pragma unroll
            for (int dd = 0; dd < 4; ++dd)
                wf[dd] = *(const float4*)&bw[(g + dd) * WSd + we];      // broadcast x8 over tr
            const float* wfp = (const float*)wf;
#pragma unroll
            for (int i = 0; i < 8; ++i) {
                const float4 xv = xf[i];
#pragma unroll
                for (int j = 0; j < 4; ++j) {
                    float a = acc[i][j];
                    a = fmaf(xv.x, wfp[0 * 4 + j], a);   // d ascending: numerics == R2
                    a = fmaf(xv.y, wfp[1 * 4 + j], a);
                    a = fmaf(xv.z, wfp[2 * 4 + j], a);
                    a = fmaf(xv.w, wfp[3 * 4 + j], a);
                    acc[i][j] = a;
                }
            }
        }
        __syncthreads();
    }

    // ---- logits -> LDS (overlay on sx: 4608 floats >= 64*65) ----
    float* sl = &sx[0][0];
#pragma unroll
    for (int i = 0; i < 8; ++i)
#pragma unroll
        for (int j = 0; j < 4; ++j)
            sl[(tr + 8 * i) * LS + we + j] = acc[i][j];
    __syncthreads();

    // ---- epilogue: wave 0, one thread per token ----
    if (tid < TOK) {
        const int t = tid;
        float m = -INFINITY;
#pragma unroll
        for (int e = 0; e < E_DIM; ++e) m = fmaxf(m, sl[t * LS + e]);

        float s = 0.0f;
#pragma unroll
        for (int e = 0; e < E_DIM; ++e) {
            const float p = expf(sl[t * LS + e] - m);
            sl[t * LS + e] = p;
            s += p;
        }
        const float inv = 1.0f / s;

        float v1 = -1.0f, v2 = -1.0f;
        int   i1 = 0,     i2 = 0;
#pragma unroll
        for (int e = 0; e < E_DIM; ++e) {
            const float p = sl[t * LS + e] * inv;
            sl[t * LS + e] = p;
            if (p > v1)      { v2 = v1; i2 = i1; v1 = p; i1 = e; }
            else if (p > v2) { v2 = p;  i2 = e; }
        }

        const float denom = v1 + v2;
        const int token = base + t;
        *(float2*)&out[(size_t)2 * token]                 = make_float2(v1 / denom, v2 / denom);
        *(float2*)&out[(size_t)2 * T + (size_t)2 * token] = make_float2((float)i1, (float)i2);
    }
    __syncthreads();

    // ---- coalesced probs write: 16 KB block region, linear float4 ----
    float* __restrict__ po = out + (size_t)4 * T + (size_t)base * E_DIM;
#pragma unroll
    for (int k = 0; k < 8; ++k) {
        const int g = (tid + k * TPB) << 2;
        const int t = g >> 6;
        const int e = g & 63;
        *(float4*)&po[g] = make_float4(sl[t * LS + e],     sl[t * LS + e + 1],
                                       sl[t * LS + e + 2], sl[t * LS + e + 3]);
    }
}

extern "C" void kernel_launch(void* const* d_in, const int* in_sizes, int n_in,
                              void* d_out, int out_size, void* d_ws, size_t ws_size,
                              hipStream_t stream) {
    const float* x  = (const float*)d_in[0];
    const float* Wg = (const float*)d_in[1];
    float* out = (float*)d_out;
    const int T = in_sizes[0] / D_DIM;   // 65536

    router_kernel<<<dim3(T / TOK), dim3(TPB), 0, stream>>>(x, Wg, out, T);
}